// Round 1
// baseline (481.841 us; speedup 1.0000x reference)
//
#include <hip/hip_runtime.h>
#include <hip/hip_bf16.h>

#define LOG2E 1.4426950408889634f

typedef __bf16 bf16x8 __attribute__((ext_vector_type(8)));
typedef __bf16 bf16x4 __attribute__((ext_vector_type(4)));
typedef float  floatx4 __attribute__((ext_vector_type(4)));

__device__ __forceinline__ floatx4 mfma16(bf16x8 a, bf16x8 b, floatx4 c) {
  return __builtin_amdgcn_mfma_f32_16x16x32_bf16(a, b, c, 0, 0, 0);
}

// ---------------------------------------------------------------------------
// Fold LoRA into weights and emit W_eff^T as bf16 [ncols][1024].
// W: [1024][ncols] fp32, La: [1024][8], Lb: [8][ncols].
// LDS-tiled transpose so both global read and write are coalesced.
// ---------------------------------------------------------------------------
__global__ __launch_bounds__(256)
void fold_wt(const float* __restrict__ W, const float* __restrict__ La,
             const float* __restrict__ Lb, __bf16* __restrict__ WT, int ncols) {
  __shared__ float tile[64][65];
  const int kt = blockIdx.y * 64, nt = blockIdx.x * 64;
  const int tx = threadIdx.x & 63, ty = threadIdx.x >> 6;
#pragma unroll
  for (int rep = 0; rep < 16; rep++) {
    int i = rep * 4 + ty;
    tile[i][tx] = W[(size_t)(kt + i) * ncols + nt + tx];
  }
  __syncthreads();
#pragma unroll
  for (int rep = 0; rep < 16; rep++) {
    int i = rep * 4 + ty;
    int n = nt + i, k = kt + tx;
    float acc = tile[tx][i];
#pragma unroll
    for (int r = 0; r < 8; r++)
      acc += 2.0f * La[k * 8 + r] * Lb[(size_t)r * ncols + n];  // LORA_SCALING = 2
    WT[(size_t)n * 1024 + k] = (__bf16)acc;
  }
}

// ---------------------------------------------------------------------------
// Cast x fp32 -> bf16 (4 elems/thread).
// ---------------------------------------------------------------------------
__global__ __launch_bounds__(256)
void cast_x(const float* __restrict__ x, __bf16* __restrict__ o) {
  int i = blockIdx.x * 256 + threadIdx.x;
  float4 v = ((const float4*)x)[i];
  bf16x4 r = {(__bf16)v.x, (__bf16)v.y, (__bf16)v.z, (__bf16)v.w};
  ((bf16x4*)o)[i] = r;
}

// ---------------------------------------------------------------------------
// 128x128 bf16 MFMA GEMM, K=1024.  C[m][n] = sum_k A[m][k] * BT[n][k].
// 4 waves (2x2), each wave 4x4 tiles of 16x16x32.  LDS stride 40 (80B):
// 16B-aligned, <=2-way bank conflicts on ds_read_b128.
// MODE 0: epilogue scatters bf16 into q/k [B,H,S,Dh] (+bias[n]); Cout=qbuf,
//         kbuf adjacent at +4194304 elems.
// MODE 1: A = Wv^T rows, BT-role = x; writes v^T bf16 [B,H,Dh,S] (+bias[m],
//         bias pointer pre-offset by 2048).
// MODE 2: fp32 C + bias[n] -> d_out [M][N] row-major.
// ---------------------------------------------------------------------------
template <int MODE>
__global__ __launch_bounds__(256)
void gemm128(const __bf16* __restrict__ A, const __bf16* __restrict__ BT,
             const float* __restrict__ bias, void* __restrict__ Cout, int N) {
  const int K = 1024;
  __shared__ __bf16 As[128 * 40];
  __shared__ __bf16 Bs[128 * 40];
  const int tid = threadIdx.x;
  const int wave = tid >> 6, lane = tid & 63;
  const int wm = wave >> 1, wn = wave & 1;
  const int quad = lane >> 4, l15 = lane & 15;
  const int m0 = blockIdx.y * 128, n0 = blockIdx.x * 128;
  const int srow = tid >> 2, sg = tid & 3;  // staging: row, 16B-granule

  floatx4 acc[4][4] = {};

  const __bf16* ap = A + (size_t)(m0 + srow) * K + sg * 8;
  const __bf16* bp = BT + (size_t)(n0 + srow) * K + sg * 8;

  for (int kb = 0; kb < K; kb += 32) {
    bf16x8 a0 = *(const bf16x8*)(ap + kb);
    bf16x8 a1 = *(const bf16x8*)(ap + (size_t)64 * K + kb);
    bf16x8 b0 = *(const bf16x8*)(bp + kb);
    bf16x8 b1 = *(const bf16x8*)(bp + (size_t)64 * K + kb);
    __syncthreads();
    *(bf16x8*)(As + srow * 40 + sg * 8) = a0;
    *(bf16x8*)(As + (srow + 64) * 40 + sg * 8) = a1;
    *(bf16x8*)(Bs + srow * 40 + sg * 8) = b0;
    *(bf16x8*)(Bs + (srow + 64) * 40 + sg * 8) = b1;
    __syncthreads();
    bf16x8 af[4], bfv[4];
#pragma unroll
    for (int t = 0; t < 4; t++) {
      af[t]  = *(const bf16x8*)(As + (wm * 64 + t * 16 + l15) * 40 + quad * 8);
      bfv[t] = *(const bf16x8*)(Bs + (wn * 64 + t * 16 + l15) * 40 + quad * 8);
    }
#pragma unroll
    for (int mi = 0; mi < 4; mi++)
#pragma unroll
      for (int ni = 0; ni < 4; ni++)
        acc[mi][ni] = mfma16(af[mi], bfv[ni], acc[mi][ni]);
  }

  // C/D layout: col = lane&15, row = quad*4 + reg  [m89/m91 verified]
#pragma unroll
  for (int mi = 0; mi < 4; mi++) {
#pragma unroll
    for (int ni = 0; ni < 4; ni++) {
      int n = n0 + wn * 64 + ni * 16 + l15;
#pragma unroll
      for (int r = 0; r < 4; r++) {
        int m = m0 + wm * 64 + mi * 16 + quad * 4 + r;
        float v = acc[mi][ni][r];
        if constexpr (MODE == 0) {
          v += bias[n];
          __bf16* qk = (__bf16*)Cout;
          int part = n >> 10, nn = n & 1023;
          int b = m >> 11, s = m & 2047;
          int h = nn >> 6, dh = nn & 63;
          qk[(size_t)part * 4194304 +
             ((size_t)((b * 16 + h) * 2048 + s)) * 64 + dh] = (__bf16)v;
        } else if constexpr (MODE == 1) {
          v += bias[m];  // bias pre-offset: W_qkv_bias + 2048
          __bf16* vt = (__bf16*)Cout;
          int h = m >> 6, dh = m & 63;
          int b = n >> 11, s = n & 2047;
          vt[((size_t)((b * 16 + h) * 64 + dh)) * 2048 + s] = (__bf16)v;
        } else {
          v += bias[n];
          ((float*)Cout)[(size_t)m * N + n] = v;
        }
      }
    }
  }
}

// ---------------------------------------------------------------------------
// Causal flash attention.  q,k: [B,H,S,64] bf16; vt: [B,H,64,S] bf16.
// Block = 4 waves x 32 q-rows = 128 q-rows; key-blocks of 128.
// Masks BEFORE scale like the reference: masked -> -1e9/8 = -1.25e8.
// ---------------------------------------------------------------------------
__global__ __launch_bounds__(256)
void flash_attn(const __bf16* __restrict__ q, const __bf16* __restrict__ k,
                const __bf16* __restrict__ vt, const int* __restrict__ amask,
                __bf16* __restrict__ ctx) {
  const int S = 2048;
  __shared__ __bf16 Qs[128 * 72];    // stride 72: 16B-aligned, 2-way max
  __shared__ __bf16 Ks[128 * 72];
  __shared__ __bf16 Vs[64 * 136];    // v^T tile: [dh][key], stride 136
  __shared__ __bf16 Ps[4][32 * 40];  // per-wave P round-trip, stride 40
  __shared__ float  s_mask[128];

  const int qb = (int)gridDim.x - 1 - (int)blockIdx.x;  // big-work blocks first
  const int bh = blockIdx.y;
  const int b = bh >> 4, h = bh & 15;
  const int tid = threadIdx.x, wave = tid >> 6, lane = tid & 63;
  const int quad = lane >> 4, l15 = lane & 15;

  const __bf16* qbase = q + (size_t)bh * S * 64 + (size_t)qb * 128 * 64;
  const __bf16* kbase = k + (size_t)bh * S * 64;
  const __bf16* vbase = vt + (size_t)bh * 64 * S;

#pragma unroll
  for (int rep = 0; rep < 4; rep++) {
    int gl = tid + rep * 256, r = gl >> 3, g = gl & 7;
    *(bf16x8*)(Qs + r * 72 + g * 8) = *(const bf16x8*)(qbase + r * 64 + g * 8);
  }

  float mst[2][4], lst[2][4];
  floatx4 oacc[2][4] = {};
#pragma unroll
  for (int mt = 0; mt < 2; mt++)
#pragma unroll
    for (int r = 0; r < 4; r++) { mst[mt][r] = -3.0e38f; lst[mt][r] = 0.0f; }

  for (int kb = 0; kb <= qb; kb++) {
    __syncthreads();
    const __bf16* kptr = kbase + (size_t)kb * 128 * 64;
#pragma unroll
    for (int rep = 0; rep < 4; rep++) {
      int gl = tid + rep * 256, r = gl >> 3, g = gl & 7;
      *(bf16x8*)(Ks + r * 72 + g * 8) = *(const bf16x8*)(kptr + r * 64 + g * 8);
    }
    const __bf16* vptr = vbase + kb * 128;
#pragma unroll
    for (int rep = 0; rep < 4; rep++) {
      int gl = tid + rep * 256, r = gl >> 4, g = gl & 15;
      *(bf16x8*)(Vs + r * 136 + g * 8) = *(const bf16x8*)(vptr + (size_t)r * S + g * 8);
    }
    if (tid < 128)
      s_mask[tid] = (amask[b * S + kb * 128 + tid] == 0) ? 1.0f : 0.0f;
    __syncthreads();

    // ---- S = Q K^T (per wave: 2 m-tiles x 8 n-tiles, 2 k-steps) ----
    floatx4 sacc[2][8] = {};
#pragma unroll
    for (int ks = 0; ks < 2; ks++) {
      bf16x8 aq0 = *(const bf16x8*)(Qs + (wave * 32 + l15) * 72 + ks * 32 + quad * 8);
      bf16x8 aq1 = *(const bf16x8*)(Qs + (wave * 32 + 16 + l15) * 72 + ks * 32 + quad * 8);
#pragma unroll
      for (int nt = 0; nt < 8; nt++) {
        bf16x8 bk = *(const bf16x8*)(Ks + (nt * 16 + l15) * 72 + ks * 32 + quad * 8);
        sacc[0][nt] = mfma16(aq0, bk, sacc[0][nt]);
        sacc[1][nt] = mfma16(aq1, bk, sacc[1][nt]);
      }
    }

    // ---- mask/scale + online softmax ----
    float alpha_[2][4];
#pragma unroll
    for (int mt = 0; mt < 2; mt++) {
#pragma unroll
      for (int r = 0; r < 4; r++) {
        int row = qb * 128 + wave * 32 + mt * 16 + quad * 4 + r;
        float rmax = -3.0e38f;
#pragma unroll
        for (int nt = 0; nt < 8; nt++) {
          int col = kb * 128 + nt * 16 + l15;
          float sv = sacc[mt][nt][r] * 0.125f;
          bool masked = (col > row) || (s_mask[nt * 16 + l15] != 0.0f);
          sv = masked ? -1.25e8f : sv;
          sacc[mt][nt][r] = sv;
          rmax = fmaxf(rmax, sv);
        }
#pragma unroll
        for (int off = 1; off < 16; off <<= 1)
          rmax = fmaxf(rmax, __shfl_xor(rmax, off, 64));
        float mnew = fmaxf(mst[mt][r], rmax);
        float al = exp2f((mst[mt][r] - mnew) * LOG2E);
        mst[mt][r] = mnew;
        float rsum = 0.0f;
#pragma unroll
        for (int nt = 0; nt < 8; nt++) {
          float p = exp2f((sacc[mt][nt][r] - mnew) * LOG2E);
          sacc[mt][nt][r] = p;
          rsum += p;
        }
#pragma unroll
        for (int off = 1; off < 16; off <<= 1)
          rsum += __shfl_xor(rsum, off, 64);
        lst[mt][r] = lst[mt][r] * al + rsum;
        alpha_[mt][r] = al;
      }
    }
#pragma unroll
    for (int mt = 0; mt < 2; mt++)
#pragma unroll
      for (int nt = 0; nt < 4; nt++)
#pragma unroll
        for (int r = 0; r < 4; r++)
          oacc[mt][nt][r] *= alpha_[mt][r];

    // ---- O += P@V in 4 chunks of 32 keys (C-layout -> A-layout via LDS).
    // Wave-private region; same-wave DS ops execute in order — compiler
    // memory barrier prevents reordering across the write->read boundary.
    __bf16* Pw = &Ps[wave][0];
#pragma unroll
    for (int kc = 0; kc < 4; kc++) {
#pragma unroll
      for (int mt = 0; mt < 2; mt++)
#pragma unroll
        for (int j = 0; j < 2; j++) {
          int nt = kc * 2 + j;
#pragma unroll
          for (int r = 0; r < 4; r++)
            Pw[(mt * 16 + quad * 4 + r) * 40 + j * 16 + l15] =
                (__bf16)sacc[mt][nt][r];
        }
      asm volatile("" ::: "memory");
      bf16x8 ap0 = *(const bf16x8*)(Pw + l15 * 40 + quad * 8);
      bf16x8 ap1 = *(const bf16x8*)(Pw + (16 + l15) * 40 + quad * 8);
#pragma unroll
      for (int nt = 0; nt < 4; nt++) {
        bf16x8 bv = *(const bf16x8*)(Vs + (nt * 16 + l15) * 136 + kc * 32 + quad * 8);
        oacc[0][nt] = mfma16(ap0, bv, oacc[0][nt]);
        oacc[1][nt] = mfma16(ap1, bv, oacc[1][nt]);
      }
      asm volatile("" ::: "memory");
    }
  }

  // ---- epilogue: ctx[b][s][h*64+dh] = O / l ----
#pragma unroll
  for (int mt = 0; mt < 2; mt++)
#pragma unroll
    for (int r = 0; r < 4; r++) {
      int s = qb * 128 + wave * 32 + mt * 16 + quad * 4 + r;
      float inv = 1.0f / lst[mt][r];
#pragma unroll
      for (int nt = 0; nt < 4; nt++) {
        int dh = nt * 16 + l15;
        ctx[((size_t)(b * 2048 + s)) * 1024 + h * 64 + dh] =
            (__bf16)(oacc[mt][nt][r] * inv);
      }
    }
}

// ---------------------------------------------------------------------------
extern "C" void kernel_launch(void* const* d_in, const int* in_sizes, int n_in,
                              void* d_out, int out_size, void* d_ws, size_t ws_size,
                              hipStream_t stream) {
  const float* x  = (const float*)d_in[0];
  const int*   am = (const int*)d_in[1];
  const float* Wq = (const float*)d_in[2];
  const float* bq = (const float*)d_in[3];
  const float* Aq = (const float*)d_in[4];
  const float* Bq = (const float*)d_in[5];
  const float* Wp = (const float*)d_in[6];
  const float* bp = (const float*)d_in[7];
  const float* Ap = (const float*)d_in[8];
  const float* Bp = (const float*)d_in[9];

  // workspace layout (48 MB total, all 16B-aligned)
  __bf16* wqkvT = (__bf16*)d_ws;                       // [3072][1024]
  __bf16* wpT   = wqkvT + (size_t)3072 * 1024;         // [1024][1024]
  __bf16* xbf   = wpT   + (size_t)1024 * 1024;         // [4096][1024]
  __bf16* qbuf  = xbf   + (size_t)4096 * 1024;         // [2][16][2048][64]
  __bf16* kbuf  = qbuf  + (size_t)4194304;             // [2][16][2048][64]
  __bf16* vtbuf = kbuf  + (size_t)4194304;             // [2][16][64][2048]
  __bf16* ctxb  = vtbuf + (size_t)4194304;             // [4096][1024]

  fold_wt<<<dim3(48, 16), 256, 0, stream>>>(Wq, Aq, Bq, wqkvT, 3072);
  fold_wt<<<dim3(16, 16), 256, 0, stream>>>(Wp, Ap, Bp, wpT, 1024);
  cast_x<<<4096, 256, 0, stream>>>(x, xbf);

  // q,k projection: M=4096, N=2048
  gemm128<0><<<dim3(16, 32), 256, 0, stream>>>(xbf, wqkvT, bq, qbuf, 2048);
  // v^T projection: A = Wv^T (rows 2048..3071 of wqkvT), "BT" role = x; M=1024, N=4096
  gemm128<1><<<dim3(32, 8), 256, 0, stream>>>(wqkvT + (size_t)2048 * 1024, xbf,
                                              bq + 2048, vtbuf, 4096);
  flash_attn<<<dim3(16, 32), 256, 0, stream>>>(qbuf, kbuf, vtbuf, am, ctxb);
  // output projection: M=4096, N=1024, fp32 out
  gemm128<2><<<dim3(8, 32), 256, 0, stream>>>(ctxb, wpT, bp, d_out, 1024);
}

// Round 2
// 324.644 us; speedup vs baseline: 1.4842x; 1.4842x over previous
//
#include <hip/hip_runtime.h>
#include <hip/hip_bf16.h>

#define LOG2E 1.4426950408889634f

typedef __bf16 bf16x8 __attribute__((ext_vector_type(8)));
typedef __bf16 bf16x4 __attribute__((ext_vector_type(4)));
typedef float  floatx4 __attribute__((ext_vector_type(4)));

__device__ __forceinline__ floatx4 mfma16(bf16x8 a, bf16x8 b, floatx4 c) {
  return __builtin_amdgcn_mfma_f32_16x16x32_bf16(a, b, c, 0, 0, 0);
}

// async global->LDS, 16B per lane. Dest = wave-uniform base + lane*16.
__device__ __forceinline__ void load_lds16(const __bf16* g, __bf16* l) {
  __builtin_amdgcn_global_load_lds(
      (const __attribute__((address_space(1))) void*)g,
      (__attribute__((address_space(3))) void*)l, 16, 0, 0);
}

// ---------------------------------------------------------------------------
// Fold LoRA into weights and emit W_eff^T as bf16 [ncols][1024].
// ---------------------------------------------------------------------------
__global__ __launch_bounds__(256)
void fold_wt(const float* __restrict__ W, const float* __restrict__ La,
             const float* __restrict__ Lb, __bf16* __restrict__ WT, int ncols) {
  __shared__ float tile[64][65];
  const int kt = blockIdx.y * 64, nt = blockIdx.x * 64;
  const int tx = threadIdx.x & 63, ty = threadIdx.x >> 6;
#pragma unroll
  for (int rep = 0; rep < 16; rep++) {
    int i = rep * 4 + ty;
    tile[i][tx] = W[(size_t)(kt + i) * ncols + nt + tx];
  }
  __syncthreads();
#pragma unroll
  for (int rep = 0; rep < 16; rep++) {
    int i = rep * 4 + ty;
    int n = nt + i, k = kt + tx;
    float acc = tile[tx][i];
#pragma unroll
    for (int r = 0; r < 8; r++)
      acc += 2.0f * La[k * 8 + r] * Lb[(size_t)r * ncols + n];  // LORA_SCALING = 2
    WT[(size_t)n * 1024 + k] = (__bf16)acc;
  }
}

__global__ __launch_bounds__(256)
void cast_x(const float* __restrict__ x, __bf16* __restrict__ o) {
  int i = blockIdx.x * 256 + threadIdx.x;
  float4 v = ((const float4*)x)[i];
  bf16x4 r = {(__bf16)v.x, (__bf16)v.y, (__bf16)v.z, (__bf16)v.w};
  ((bf16x4*)o)[i] = r;
}

// ---------------------------------------------------------------------------
// 128x128 bf16 MFMA GEMM, K=1024, BK=64, global_load_lds staging with
// XOR-swizzled LDS (chunk ^= row&7; rows 64 bf16 = 8 x 16B chunks).
// MODE 0: bf16 scatter into q/k [B,H,S,Dh] (+bias[n]).
// MODE 1: A=Wv^T, BT-role=x; bf16 v^T [B,H,Dh,S] (+bias[m], bias pre-offset).
// MODE 2: fp32 C + bias[n] -> [M][N].
// ---------------------------------------------------------------------------
template <int MODE>
__global__ __launch_bounds__(256)
void gemm128(const __bf16* __restrict__ A, const __bf16* __restrict__ BT,
             const float* __restrict__ bias, void* __restrict__ Cout, int N) {
  const int K = 1024;
  __shared__ alignas(16) __bf16 As[128 * 64];
  __shared__ alignas(16) __bf16 Bs[128 * 64];
  const int tid = threadIdx.x;
  const int wave = tid >> 6, lane = tid & 63;
  const int wm = wave >> 1, wn = wave & 1;
  const int quad = lane >> 4, l15 = lane & 15;
  const int m0 = blockIdx.y * 128, n0 = blockIdx.x * 128;
  const int srow8 = lane >> 3, sc8 = lane & 7;   // staging: 8 rows x 8 chunks
  const int sswz = sc8 ^ srow8;

  floatx4 acc[4][4] = {};

  for (int kb = 0; kb < K; kb += 64) {
    __syncthreads();
#pragma unroll
    for (int t = 0; t < 4; t++) {
      int rbase = (wave * 4 + t) * 8;
      int row = rbase + srow8;
      load_lds16(A + (size_t)(m0 + row) * K + kb + sswz * 8, As + rbase * 64);
      load_lds16(BT + (size_t)(n0 + row) * K + kb + sswz * 8, Bs + rbase * 64);
    }
    __syncthreads();
#pragma unroll
    for (int ks = 0; ks < 2; ks++) {
      bf16x8 af[4], bfv[4];
#pragma unroll
      for (int t = 0; t < 4; t++) {
        int ra = wm * 64 + t * 16 + l15;
        int rb = wn * 64 + t * 16 + l15;
        int ch = (ks * 4 + quad) ^ (l15 & 7);
        af[t]  = *(const bf16x8*)(As + ra * 64 + ch * 8);
        bfv[t] = *(const bf16x8*)(Bs + rb * 64 + ch * 8);
      }
#pragma unroll
      for (int mi = 0; mi < 4; mi++)
#pragma unroll
        for (int ni = 0; ni < 4; ni++)
          acc[mi][ni] = mfma16(af[mi], bfv[ni], acc[mi][ni]);
    }
  }

  // C/D: col = lane&15, row = quad*4 + reg
#pragma unroll
  for (int mi = 0; mi < 4; mi++) {
#pragma unroll
    for (int ni = 0; ni < 4; ni++) {
      int n = n0 + wn * 64 + ni * 16 + l15;
#pragma unroll
      for (int r = 0; r < 4; r++) {
        int m = m0 + wm * 64 + mi * 16 + quad * 4 + r;
        float v = acc[mi][ni][r];
        if constexpr (MODE == 0) {
          v += bias[n];
          __bf16* qk = (__bf16*)Cout;
          int part = n >> 10, nn = n & 1023;
          int b = m >> 11, s = m & 2047;
          int h = nn >> 6, dh = nn & 63;
          qk[(size_t)part * 4194304 +
             ((size_t)((b * 16 + h) * 2048 + s)) * 64 + dh] = (__bf16)v;
        } else if constexpr (MODE == 1) {
          v += bias[m];
          __bf16* vt = (__bf16*)Cout;
          int h = m >> 6, dh = m & 63;
          int b = n >> 11, s = n & 2047;
          vt[((size_t)((b * 16 + h) * 64 + dh)) * 2048 + s] = (__bf16)v;
        } else {
          v += bias[n];
          ((float*)Cout)[(size_t)m * N + n] = v;
        }
      }
    }
  }
}

// ---------------------------------------------------------------------------
// Causal flash attention, S^T formulation.
// q,k: [B,H,S,64] bf16; vt: [B,H,64,S] bf16.  Block: 4 waves x 32 q = 128 q.
// S^T = K·Q^T so softmax is in-register per q (l15 = q); P written as packed
// b64 to per-wave LDS chunk, read back as A-frags for O = P·V.
// Masks BEFORE scale like the reference: masked -> -1e9/8 = -1.25e8.
// ---------------------------------------------------------------------------
__global__ __launch_bounds__(256)
void flash_attn(const __bf16* __restrict__ q, const __bf16* __restrict__ k,
                const __bf16* __restrict__ vt, const int* __restrict__ amask,
                __bf16* __restrict__ ctx) {
  const int S = 2048;
  __shared__ alignas(16) __bf16 Qs[128 * 64];   // swizzled, 8 chunks/row
  __shared__ alignas(16) __bf16 Ks[128 * 64];
  __shared__ alignas(16) __bf16 Vs[64 * 128];   // v^T tile [dh][key], 16 chunks/row
  __shared__ alignas(16) __bf16 PTs[4][32 * 40];  // per-wave P [q][32 keys+pad]

  const int qb = (int)gridDim.x - 1 - (int)blockIdx.x;  // big blocks first
  const int bh = blockIdx.y, b = bh >> 4, h = bh & 15;
  const int tid = threadIdx.x, wave = tid >> 6, lane = tid & 63;
  const int quad = lane >> 4, l15 = lane & 15;
  const int srow8 = lane >> 3, sc8 = lane & 7;
  const int srow16 = lane >> 4, sc16 = lane & 15;

  const __bf16* qbase = q + (size_t)bh * S * 64 + (size_t)qb * 128 * 64;
  const __bf16* kbase = k + (size_t)bh * S * 64;
  const __bf16* vbase = vt + (size_t)bh * 64 * S;

  // Stage Q once: per call 8 rows x 128B, swizzle chunk^row&7
#pragma unroll
  for (int t = 0; t < 4; t++) {
    int rbase = (wave * 4 + t) * 8;
    load_lds16(qbase + (rbase + srow8) * 64 + (sc8 ^ srow8) * 8, Qs + rbase * 64);
  }

  float mrun[2] = {-3.0e38f, -3.0e38f};
  float lrun[2] = {0.0f, 0.0f};
  floatx4 oacc[2][4] = {};
  const int qg0 = qb * 128 + wave * 32 + l15;  // lane's q (tile mt adds 16)

  for (int kb = 0; kb <= qb; kb++) {
    __syncthreads();
    const __bf16* kptr = kbase + (size_t)kb * 128 * 64;
#pragma unroll
    for (int t = 0; t < 4; t++) {
      int rbase = (wave * 4 + t) * 8;
      load_lds16(kptr + (rbase + srow8) * 64 + (sc8 ^ srow8) * 8, Ks + rbase * 64);
    }
    const __bf16* vptr = vbase + kb * 128;
#pragma unroll
    for (int t = 0; t < 4; t++) {
      int rbase = (wave * 4 + t) * 4;
      int rr = rbase + srow16;
      load_lds16(vptr + (size_t)rr * S + (sc16 ^ (rr & 7)) * 8, Vs + rbase * 128);
    }
    // padding mask as per-wave ballot bitmasks (no LDS)
    unsigned long long pm0 = __ballot(amask[b * S + kb * 128 + lane] == 0);
    unsigned long long pm1 = __ballot(amask[b * S + kb * 128 + 64 + lane] == 0);
    __syncthreads();

    // ---- S^T = K Q^T : st[key-tile][q-tile]; col(l15)=q, row(quad*4+r)=key
    floatx4 st[8][2] = {};
#pragma unroll
    for (int ks = 0; ks < 2; ks++) {
      bf16x8 qf[2];
#pragma unroll
      for (int mt = 0; mt < 2; mt++) {
        int row = wave * 32 + mt * 16 + l15;
        qf[mt] = *(const bf16x8*)(Qs + row * 64 + (((ks << 2) + quad) ^ (l15 & 7)) * 8);
      }
#pragma unroll
      for (int nt = 0; nt < 8; nt++) {
        int row = nt * 16 + l15;
        bf16x8 kf = *(const bf16x8*)(Ks + row * 64 + (((ks << 2) + quad) ^ (l15 & 7)) * 8);
        st[nt][0] = mfma16(kf, qf[0], st[nt][0]);
        st[nt][1] = mfma16(kf, qf[1], st[nt][1]);
      }
    }

    // ---- mask (before scale, like reference) ----
#pragma unroll
    for (int nt = 0; nt < 8; nt++) {
      unsigned long long pm = (nt < 4) ? pm0 : pm1;
      int klbase = (nt & 3) * 16 + quad * 4;       // bit index base
      int colbase = kb * 128 + nt * 16 + quad * 4; // global key index base
#pragma unroll
      for (int r = 0; r < 4; r++) {
        bool pad = (pm >> (klbase + r)) & 1ull;
#pragma unroll
        for (int mt = 0; mt < 2; mt++) {
          float sv = st[nt][mt][r] * 0.125f;
          bool masked = pad || (colbase + r > qg0 + mt * 16);
          st[nt][mt][r] = masked ? -1.25e8f : sv;
        }
      }
    }

    // ---- online softmax: in-register over 32 vals, 2 cross-quad shuffles ----
    float al[2];
#pragma unroll
    for (int mt = 0; mt < 2; mt++) {
      float rm = -3.0e38f;
#pragma unroll
      for (int nt = 0; nt < 8; nt++)
#pragma unroll
        for (int r = 0; r < 4; r++) rm = fmaxf(rm, st[nt][mt][r]);
      rm = fmaxf(rm, __shfl_xor(rm, 16, 64));
      rm = fmaxf(rm, __shfl_xor(rm, 32, 64));
      float mnew = fmaxf(mrun[mt], rm);
      al[mt] = exp2f((mrun[mt] - mnew) * LOG2E);
      mrun[mt] = mnew;
      float rs = 0.0f;
#pragma unroll
      for (int nt = 0; nt < 8; nt++)
#pragma unroll
        for (int r = 0; r < 4; r++) {
          float p = exp2f((st[nt][mt][r] - mnew) * LOG2E);
          st[nt][mt][r] = p;
          rs += p;
        }
      rs += __shfl_xor(rs, 16, 64);
      rs += __shfl_xor(rs, 32, 64);
      lrun[mt] = lrun[mt] * al[mt] + rs;
    }

    // rescale O: alpha per O-row (quad*4+r) fetched cross-lane
#pragma unroll
    for (int mt = 0; mt < 2; mt++) {
      float ar[4];
#pragma unroll
      for (int r = 0; r < 4; r++) ar[r] = __shfl(al[mt], quad * 4 + r, 64);
#pragma unroll
      for (int nd = 0; nd < 4; nd++)
#pragma unroll
        for (int r = 0; r < 4; r++) oacc[mt][nd][r] *= ar[r];
    }

    // ---- O += P V, 4 chunks of 32 keys; P via packed b64 LDS round-trip ----
    __bf16* Pw = &PTs[wave][0];
#pragma unroll
    for (int kc = 0; kc < 4; kc++) {
#pragma unroll
      for (int mt = 0; mt < 2; mt++)
#pragma unroll
        for (int j = 0; j < 2; j++) {
          int nt = kc * 2 + j;
          bf16x4 pk = {(__bf16)st[nt][mt][0], (__bf16)st[nt][mt][1],
                       (__bf16)st[nt][mt][2], (__bf16)st[nt][mt][3]};
          *(bf16x4*)(Pw + (mt * 16 + l15) * 40 + j * 16 + quad * 4) = pk;
        }
      asm volatile("" ::: "memory");  // same-wave DS ops are in-order
      bf16x8 pf0 = *(const bf16x8*)(Pw + l15 * 40 + quad * 8);
      bf16x8 pf1 = *(const bf16x8*)(Pw + (16 + l15) * 40 + quad * 8);
#pragma unroll
      for (int nd = 0; nd < 4; nd++) {
        int row = nd * 16 + l15;
        bf16x8 vf = *(const bf16x8*)(Vs + row * 128 + ((kc * 4 + quad) ^ (l15 & 7)) * 8);
        oacc[0][nd] = mfma16(pf0, vf, oacc[0][nd]);
        oacc[1][nd] = mfma16(pf1, vf, oacc[1][nd]);
      }
      asm volatile("" ::: "memory");
    }
  }

  // ---- epilogue: ctx[b][s][h*64+dh] = O / l ;  O rows = quad*4+r ----
#pragma unroll
  for (int mt = 0; mt < 2; mt++) {
    float lr[4];
#pragma unroll
    for (int r = 0; r < 4; r++)
      lr[r] = 1.0f / __shfl(lrun[mt], quad * 4 + r, 64);
#pragma unroll
    for (int nd = 0; nd < 4; nd++) {
#pragma unroll
      for (int r = 0; r < 4; r++) {
        int s = qb * 128 + wave * 32 + mt * 16 + quad * 4 + r;
        int dh = nd * 16 + l15;
        ctx[((size_t)(b * 2048 + s)) * 1024 + h * 64 + dh] =
            (__bf16)(oacc[mt][nd][r] * lr[r]);
      }
    }
  }
}

// ---------------------------------------------------------------------------
extern "C" void kernel_launch(void* const* d_in, const int* in_sizes, int n_in,
                              void* d_out, int out_size, void* d_ws, size_t ws_size,
                              hipStream_t stream) {
  const float* x  = (const float*)d_in[0];
  const int*   am = (const int*)d_in[1];
  const float* Wq = (const float*)d_in[2];
  const float* bq = (const float*)d_in[3];
  const float* Aq = (const float*)d_in[4];
  const float* Bq = (const float*)d_in[5];
  const float* Wp = (const float*)d_in[6];
  const float* bp = (const float*)d_in[7];
  const float* Ap = (const float*)d_in[8];
  const float* Bp = (const float*)d_in[9];

  __bf16* wqkvT = (__bf16*)d_ws;                       // [3072][1024]
  __bf16* wpT   = wqkvT + (size_t)3072 * 1024;         // [1024][1024]
  __bf16* xbf   = wpT   + (size_t)1024 * 1024;         // [4096][1024]
  __bf16* qbuf  = xbf   + (size_t)4096 * 1024;         // [2][16][2048][64]
  __bf16* kbuf  = qbuf  + (size_t)4194304;             // [2][16][2048][64]
  __bf16* vtbuf = kbuf  + (size_t)4194304;             // [2][16][64][2048]
  __bf16* ctxb  = vtbuf + (size_t)4194304;             // [4096][1024]

  fold_wt<<<dim3(48, 16), 256, 0, stream>>>(Wq, Aq, Bq, wqkvT, 3072);
  fold_wt<<<dim3(16, 16), 256, 0, stream>>>(Wp, Ap, Bp, wpT, 1024);
  cast_x<<<4096, 256, 0, stream>>>(x, xbf);

  gemm128<0><<<dim3(16, 32), 256, 0, stream>>>(xbf, wqkvT, bq, qbuf, 2048);
  gemm128<1><<<dim3(32, 8), 256, 0, stream>>>(wqkvT + (size_t)2048 * 1024, xbf,
                                              bq + 2048, vtbuf, 4096);
  flash_attn<<<dim3(16, 32), 256, 0, stream>>>(qbuf, kbuf, vtbuf, am, ctxb);
  gemm128<2><<<dim3(8, 32), 256, 0, stream>>>(ctxb, wpT, bp, d_out, 1024);
}